// Round 19
// baseline (227.083 us; speedup 1.0000x reference)
//
#include <hip/hip_runtime.h>
#include <stdint.h>

// ---- problem constants (fixed by setup_inputs) ----
#define B_   4
#define C_   256
#define CI_  128
#define T_   16
#define H_   28
#define W_   28
#define HW_  784          // H*W
#define N_   12544        // T*H*W
#define TP_  8
#define HP_  14
#define WP_  14
#define NP_  1568         // pooled positions = 49*32 exactly
#define NP2_ 1600         // padded to 25*64 (pool/g layout only)
#define NT_  196          // N/64  (64-row kernels)
#define NT2_ 98           // N/128 (k_attn 128-query blocks)
#define NBLK_ 784         // B*NT
#define NBLK2_ 392        // B*NT2
#define KVB_ 32           // key tile for k_attn
#define NKT_ 49           // NP_/KVB_
#define LOG2E_ 1.4426950408889634f

typedef __attribute__((ext_vector_type(8))) __bf16 bf16x8;
typedef __attribute__((ext_vector_type(4))) float  f32x4;

#define MFMA(a,b,c) __builtin_amdgcn_mfma_f32_16x16x32_bf16(a,b,c,0,0,0)

__device__ __forceinline__ void split_bf16(float f, __bf16& hi, __bf16& lo){
  hi = (__bf16)f;
  lo = (__bf16)(f - (float)hi);
}

__device__ __forceinline__ uint32_t pack2(float a, float b){
  union { __bf16 h; unsigned short s; } ua, ub;
  ua.h = (__bf16)a; ub.h = (__bf16)b;
  return (uint32_t)ua.s | ((uint32_t)ub.s << 16);
}

__device__ __forceinline__ void gload_lds16(const void* g, void* l){
  __builtin_amdgcn_global_load_lds((const __attribute__((address_space(1))) void*)g,
                                   (__attribute__((address_space(3))) void*)l, 16, 0, 0);
}

// ---------------- K0w: split weights fp32 -> bf16 hi/lo ----------------
__global__ __launch_bounds__(256) void k_wconv(const float* __restrict__ wt, const float* __restrict__ wp,
                       const float* __restrict__ wg, const float* __restrict__ zw,
                       __bf16* __restrict__ wth, __bf16* __restrict__ wtl,
                       __bf16* __restrict__ wph, __bf16* __restrict__ wpl,
                       __bf16* __restrict__ wgh, __bf16* __restrict__ wgl,
                       __bf16* __restrict__ zwh, __bf16* __restrict__ zwl){
  int i = blockIdx.x*256 + threadIdx.x;
  if (i < 32768){
    __bf16 h, lo;
    split_bf16(wt[i], h, lo); wth[i]=h; wtl[i]=lo;
    split_bf16(wp[i], h, lo); wph[i]=h; wpl[i]=lo;
    split_bf16(wg[i], h, lo); wgh[i]=h; wgl[i]=lo;
    split_bf16(zw[i], h, lo); zwh[i]=h; zwl[i]=lo;
  }
}

// ---------------- K1: projections; x read DIRECT (fp32, strided) + on-the-fly split ----------------
// theta stored pre-scaled by log2e (exact exp2 substitution in k_attn).
// g projection 2-term (x_hi*w_lo dropped: ~0.001 abs, << g bf16 rounding).
__global__ __launch_bounds__(256,4) void k_proj3(const float* __restrict__ x,
                        const __bf16* __restrict__ wth, const __bf16* __restrict__ wtl,
                        const __bf16* __restrict__ wph, const __bf16* __restrict__ wpl,
                        const __bf16* __restrict__ wgh, const __bf16* __restrict__ wgl,
                        __bf16* __restrict__ th_hi, __bf16* __restrict__ th_lo,
                        float* __restrict__ phf32, __bf16* __restrict__ ggf){
  __shared__ char wbuf[2][16384];   // [hi 8KB | lo 8KB], 16 rows x 512B, swizzled
  int wg = blockIdx.x;
  int nt = wg % NT_; int b = wg/NT_;
  int n0 = nt*64;
  int tid = threadIdx.x; int w = tid>>6; int l = tid&63; int lr = l&15; int lg = l>>4;
  int nrow = 16*w + lr;
  const float* xb = x + (size_t)b*C_*N_ + (n0 + nrow);
  bf16x8 Ah[8], Al[8];
  #pragma unroll
  for (int ks=0; ks<8; ++ks){
    #pragma unroll
    for (int j=0;j<8;++j){
      float v = xb[(size_t)(32*ks + 8*lg + j)*N_];
      __bf16 hi, lo; split_bf16(v, hi, lo);
      Ah[ks][j] = hi; Al[ks][j] = lo;
    }
  }
  int sp_part[4]; int sp_rowc[4]; int sp_off[4];
  #pragma unroll
  for (int i=0;i<4;++i){
    int p = i*4096 + tid*16;
    sp_part[i] = p>>13;                       // 0 hi, 1 lo
    int row = (p>>9)&15;
    int colb = p & 511;
    sp_rowc[i] = row*C_ + ((colb ^ ((row&7)<<4)) >> 1);
    sp_off[i] = i*4096 + w*1024;
  }
  #pragma unroll
  for (int i=0;i<4;++i){
    const __bf16* src = (sp_part[i] ? wtl : wth) + sp_rowc[i];
    gload_lds16(src, &wbuf[0][sp_off[i]]);
  }
  __syncthreads();

  size_t obase = ((size_t)(b*N_ + n0))*CI_;
  int cur = 0;
  for (int pair=0; pair<24; ++pair){
    int p = pair>>3, ot = pair&7;
    if (pair < 23){
      int pn = pair+1, p2 = pn>>3, ot2 = pn&7;
      const __bf16* bh = (p2==0) ? wth : ((p2==1) ? wph : wgh);
      const __bf16* bl = (p2==0) ? wtl : ((p2==1) ? wpl : wgl);
      #pragma unroll
      for (int i=0;i<4;++i){
        const __bf16* src = (sp_part[i] ? bl : bh) + (size_t)(16*ot2)*C_ + sp_rowc[i];
        gload_lds16(src, &wbuf[cur^1][sp_off[i]]);
      }
    }
    const char* wb = wbuf[cur];
    f32x4 aHH={0.f,0.f,0.f,0.f}, aLH={0.f,0.f,0.f,0.f}, aHL={0.f,0.f,0.f,0.f};
    int swz = (lr&7)<<4;
    if (p < 2){
      #pragma unroll
      for (int ks=0; ks<8; ++ks){
        int off = lr*512 + ((ks*64 + lg*16) ^ swz);
        bf16x8 Bh = *(const bf16x8*)(wb + off);
        bf16x8 Bl = *(const bf16x8*)(wb + 8192 + off);
        aHH = MFMA(Ah[ks], Bh, aHH);
        aLH = MFMA(Al[ks], Bh, aLH);
        aHL = MFMA(Ah[ks], Bl, aHL);
      }
    } else {
      #pragma unroll
      for (int ks=0; ks<8; ++ks){
        int off = lr*512 + ((ks*64 + lg*16) ^ swz);
        bf16x8 Bh = *(const bf16x8*)(wb + off);
        aHH = MFMA(Ah[ks], Bh, aHH);
        aLH = MFMA(Al[ks], Bh, aLH);
      }
    }
    f32x4 acc = aHH + aLH + aHL;
    if (p == 0){
      #pragma unroll
      for (int r=0;r<4;++r){
        int n = 16*w + 4*lg + r;
        float sv = acc[r] * LOG2E_;
        __bf16 hi, lo; split_bf16(sv, hi, lo);
        th_hi[obase + (size_t)n*CI_ + 16*ot + lr] = hi;
        th_lo[obase + (size_t)n*CI_ + 16*ot + lr] = lo;
      }
    } else if (p == 1){
      #pragma unroll
      for (int r=0;r<4;++r){
        int n = 16*w + 4*lg + r;
        phf32[obase + (size_t)n*CI_ + 16*ot + lr] = acc[r];
      }
    } else {
      #pragma unroll
      for (int r=0;r<4;++r){
        int n = 16*w + 4*lg + r;
        ggf[obase + (size_t)n*CI_ + 16*ot + lr] = (__bf16)acc[r];
      }
    }
    __syncthreads();
    cur ^= 1;
  }
}

// ---------------- K2: maxpool + fused phmean partials ----------------
// Block = 16 m-values x 16 c8-groups (fixed b). Partial sum over block's m -> pph[blk][128].
__global__ __launch_bounds__(256) void k_pool(const float* __restrict__ phf32, const __bf16* __restrict__ ggf,
                       __bf16* __restrict__ phph, __bf16* __restrict__ phpl,
                       __bf16* __restrict__ ggp, float* __restrict__ pph){
  __shared__ float red[16][128];
  int blk = blockIdx.x;            // 400 = B * 100
  int tid = threadIdx.x;
  int idx = blk*256 + tid;
  int c8 = idx & 15;
  int m  = (idx>>4) % NP2_;
  int b  = idx / (16*NP2_);
  bool valid = (m < NP_);
  float mp[8], mg[8];
  #pragma unroll
  for (int j=0;j<8;++j){ mp[j] = 0.f; mg[j] = 0.f; }
  if (valid){
    #pragma unroll
    for (int j=0;j<8;++j){ mp[j] = -3e38f; mg[j] = -3e38f; }
    int tp = m/(HP_*WP_), hp = (m/WP_)%HP_, wq = m%WP_;
    int t0 = tp*2, h0 = hp*2, w0 = wq*2;
    const float*  pb = phf32 + ((size_t)b*N_)*CI_ + c8*8;
    const __bf16* gb = ggf   + ((size_t)b*N_)*CI_ + c8*8;
    #pragma unroll
    for (int dt=0; dt<2; ++dt)
    #pragma unroll
    for (int dh=0; dh<2; ++dh)
    #pragma unroll
    for (int dw=0; dw<2; ++dw){
      int n = (t0+dt)*HW_ + (h0+dh)*W_ + (w0+dw);
      f32x4 p0 = *(const f32x4*)(pb + (size_t)n*CI_);
      f32x4 p1 = *(const f32x4*)(pb + (size_t)n*CI_ + 4);
      bf16x8 vg = *(const bf16x8*)(gb + (size_t)n*CI_);
      #pragma unroll
      for (int j=0;j<4;++j){ mp[j] = fmaxf(mp[j], p0[j]); mp[4+j] = fmaxf(mp[4+j], p1[j]); }
      #pragma unroll
      for (int j=0;j<8;++j){ mg[j] = fmaxf(mg[j], (float)vg[j]); }
    }
  }
  bf16x8 oh, ol, og;
  #pragma unroll
  for (int j=0;j<8;++j){
    __bf16 hi, lo;
    split_bf16(mp[j], hi, lo);
    oh[j] = hi; ol[j] = lo;
    og[j] = (__bf16)mg[j];
  }
  *(bf16x8*)(phph + ((size_t)(b*NP2_ + m))*CI_ + c8*8) = oh;
  *(bf16x8*)(phpl + ((size_t)(b*NP2_ + m))*CI_ + c8*8) = ol;
  #pragma unroll
  for (int j=0;j<8;++j) ggp[((size_t)(b*CI_ + c8*8 + j))*NP2_ + m] = og[j];
  // fused phmean partial: sum over this block's 16 m values
  int ms = tid >> 4;
  #pragma unroll
  for (int j=0;j<8;++j) red[ms][c8*8 + j] = mp[j];
  __syncthreads();
  if (tid < 128){
    float s = 0.f;
    #pragma unroll
    for (int k=0;k<16;++k) s += red[k][tid];
    pph[(size_t)blk*128 + tid] = s;
  }
}

// ---------------- K2b: reduce pph[400][128] -> phmean[b][c] ----------------
__global__ __launch_bounds__(256) void k_phmean2(const float* __restrict__ pph, float* __restrict__ phmean){
  int t = blockIdx.x*256 + threadIdx.x;
  if (t >= B_*CI_) return;
  int b = t >> 7, c = t & 127;
  float s = 0.f;
  for (int k=0; k<100; ++k) s += pph[(size_t)(b*100+k)*128 + c];
  phmean[b*CI_ + c] = s * (1.0f/(float)NP_);
}

// ---------------- K3: attention; 4 waves x 32 query-cols (2 col-groups); exp2 softmax; y bf16 ----------------
// (256,2): VGPR+AGPR ~216 needs cap 256 -> no spill (verified r15/r17).
__global__ __launch_bounds__(256,2) void k_attn(const __bf16* __restrict__ th_hi, const __bf16* __restrict__ th_lo,
                       const __bf16* __restrict__ phph, const __bf16* __restrict__ phpl,
                       const __bf16* __restrict__ ggp, const float* __restrict__ phmean,
                       __bf16* __restrict__ y){
  __shared__ char sbuf[2][24576];   // [phiH 8KB | phiL 8KB | g 8KB]
  __shared__ float estp[128][2];
  __shared__ float est[128];
  int wg = blockIdx.x;
  int nt = wg % NT2_; int b = wg/NT2_;
  int n0 = nt*128;
  int tid = threadIdx.x; int w = tid>>6; int l = tid&63; int lr = l&15; int lg = l>>4;
  const __bf16* phb = phph + (size_t)b*NP2_*CI_;
  const __bf16* plb = phpl + (size_t)b*NP2_*CI_;
  const __bf16* ggb = ggp + (size_t)b*CI_*NP2_;

  // --- est[row] = theta'(n0+row) . phmean[b]  (theta' pre-scaled by log2e) ---
  {
    int row = tid >> 1, q = tid & 1;
    const __bf16* rh = th_hi + ((size_t)(b*N_ + n0 + row))*CI_ + 64*q;
    const __bf16* rl = th_lo + ((size_t)(b*N_ + n0 + row))*CI_ + 64*q;
    const float* pm = phmean + b*CI_ + 64*q;
    float sacc = 0.f;
    #pragma unroll
    for (int j=0;j<8;++j){
      bf16x8 vh = *(const bf16x8*)(rh + 8*j);
      bf16x8 vl = *(const bf16x8*)(rl + 8*j);
      f32x4 p0 = *(const f32x4*)(pm + 8*j);
      f32x4 p1 = *(const f32x4*)(pm + 8*j + 4);
      #pragma unroll
      for (int k=0;k<4;++k){
        sacc += ((float)vh[k]   + (float)vl[k]  )*p0[k];
        sacc += ((float)vh[4+k] + (float)vl[4+k])*p1[k];
      }
    }
    estp[row][q] = sacc;
  }
  // --- staging descriptors: 6 global_load_lds per wave per tile (4 waves x 6 = 24) ---
  const __bf16* sptr[6]; int sstr[6]; int soff[6];
  #pragma unroll
  for (int jj=0; jj<6; ++jj){
    int j = w*6 + jj;              // 0..23
    int p = j*1024 + l*16;         // byte within 24KB tile
    int reg = p >> 13;             // 0 phiH, 1 phiL, 2 g
    int e = p & 8191;
    if (reg < 2){
      int m = e >> 8;
      int chb = (e & 255) ^ ((m & 7) << 4);
      const __bf16* base = (reg==0 ? phb : plb);
      sptr[jj] = base + (size_t)m*CI_ + (chb>>1);
      sstr[jj] = KVB_*CI_;
    } else {
      int c = e >> 6;
      int chb = (e & 63) ^ (((c >> 1) & 3) << 4);   // decorrelated swizzle (matches read)
      sptr[jj] = ggb + (size_t)c*NP2_ + (chb>>1);
      sstr[jj] = KVB_;
    }
    soff[jj] = j*1024;             // wave-uniform LDS base (HW adds lane*16)
  }
  __syncthreads();
  if (tid < 128) est[tid] = estp[tid][0]+estp[tid][1];

  // theta fragments for 2 col-groups: cols n0 + 32w + 16cg + lr
  bf16x8 Ah[2][4], Al[2][4];
  #pragma unroll
  for (int cg=0; cg<2; ++cg){
    size_t tb = ((size_t)(b*N_ + n0 + 32*w + 16*cg))*CI_ + (size_t)lr*CI_;
    #pragma unroll
    for (int ks=0; ks<4; ++ks){
      Ah[cg][ks] = *(const bf16x8*)(th_hi + tb + 32*ks + 8*lg);
      Al[cg][ks] = *(const bf16x8*)(th_lo + tb + 32*ks + 8*lg);
    }
  }
  f32x4 yacc0[8], yacc1[8];
  #pragma unroll
  for (int ct=0; ct<8; ++ct){ yacc0[ct] = (f32x4){0.f,0.f,0.f,0.f}; yacc1[ct] = (f32x4){0.f,0.f,0.f,0.f}; }
  float psum0 = 0.f, psum1 = 0.f;
  __syncthreads();
  float estl0 = est[32*w + lr];
  float estl1 = est[32*w + 16 + lr];

  // prologue: stage tile 0
  #pragma unroll
  for (int jj=0; jj<6; ++jj) gload_lds16(sptr[jj], &sbuf[0][soff[jj]]);
  __syncthreads();

  int s1 = lr + (((2*lg)  )&3)*16;   // source lanes for PA assembly
  int s2 = lr + (((2*lg+1))&3)*16;
  bool hi2 = (lg >= 2);

  int cur = 0;
  for (int t=0; t<NKT_; ++t){
    if (t < NKT_-1){
      #pragma unroll
      for (int jj=0; jj<6; ++jj)
        gload_lds16(sptr[jj] + (size_t)(t+1)*sstr[jj], &sbuf[cur^1][soff[jj]]);
    }
    const char* pb_ = sbuf[cur];
    // ---- swapped QK (3-term), both col-groups share phi fragment reads ----
    uint32_t qa00, qa01, qa10, qa11, qb00, qb01, qb10, qb11;
    #pragma unroll
    for (int mt=0; mt<2; ++mt){
      f32x4 aHH0={0.f,0.f,0.f,0.f}, aLH0={0.f,0.f,0.f,0.f}, aHL0={0.f,0.f,0.f,0.f};
      f32x4 aHH1={0.f,0.f,0.f,0.f}, aLH1={0.f,0.f,0.f,0.f}, aHL1={0.f,0.f,0.f,0.f};
      int mrow = 16*mt + lr;
      int swz = (mrow&7)<<4;
      #pragma unroll
      for (int ks=0; ks<4; ++ks){
        int off = mrow*256 + ((64*ks + 16*lg) ^ swz);
        bf16x8 Bh = *(const bf16x8*)(pb_ + off);
        bf16x8 Bl = *(const bf16x8*)(pb_ + 8192 + off);
        aHH0 = MFMA(Bh, Ah[0][ks], aHH0);
        aLH0 = MFMA(Bh, Al[0][ks], aLH0);
        aHL0 = MFMA(Bl, Ah[0][ks], aHL0);
        aHH1 = MFMA(Bh, Ah[1][ks], aHH1);
        aLH1 = MFMA(Bh, Al[1][ks], aLH1);
        aHL1 = MFMA(Bl, Ah[1][ks], aHL1);
      }
      f32x4 sv0 = aHH0 + aLH0 + aHL0;
      f32x4 sv1 = aHH1 + aLH1 + aHL1;
      float p00 = exp2f(sv0[0]-estl0), p01 = exp2f(sv0[1]-estl0);
      float p02 = exp2f(sv0[2]-estl0), p03 = exp2f(sv0[3]-estl0);
      float p10 = exp2f(sv1[0]-estl1), p11 = exp2f(sv1[1]-estl1);
      float p12 = exp2f(sv1[2]-estl1), p13 = exp2f(sv1[3]-estl1);
      psum0 += (p00 + p01) + (p02 + p03);
      psum1 += (p10 + p11) + (p12 + p13);
      uint32_t da0 = pack2(p00,p01), da1 = pack2(p02,p03);
      uint32_t db0 = pack2(p10,p11), db1 = pack2(p12,p13);
      if (mt == 0){ qa00 = da0; qa01 = da1; qb00 = db0; qb01 = db1; }
      else        { qa10 = da0; qa11 = da1; qb10 = db0; qb11 = db1; }
    }
    // ---- assemble PA for each col-group ----
    uint32_t ba00 = __shfl(qa00, s1, 64), ba10 = __shfl(qa10, s1, 64);
    uint32_t ba01 = __shfl(qa01, s1, 64), ba11 = __shfl(qa11, s1, 64);
    uint32_t ca00 = __shfl(qa00, s2, 64), ca10 = __shfl(qa10, s2, 64);
    uint32_t ca01 = __shfl(qa01, s2, 64), ca11 = __shfl(qa11, s2, 64);
    union { uint32_t u[4]; bf16x8 v; } pa0;
    pa0.u[0] = hi2 ? ba10 : ba00;
    pa0.u[1] = hi2 ? ba11 : ba01;
    pa0.u[2] = hi2 ? ca10 : ca00;
    pa0.u[3] = hi2 ? ca11 : ca01;
    uint32_t bb00 = __shfl(qb00, s1, 64), bb10 = __shfl(qb10, s1, 64);
    uint32_t bb01 = __shfl(qb01, s1, 64), bb11 = __shfl(qb11, s1, 64);
    uint32_t cb00 = __shfl(qb00, s2, 64), cb10 = __shfl(qb10, s2, 64);
    uint32_t cb01 = __shfl(qb01, s2, 64), cb11 = __shfl(qb11, s2, 64);
    union { uint32_t u[4]; bf16x8 v; } pa1;
    pa1.u[0] = hi2 ? bb10 : bb00;
    pa1.u[1] = hi2 ? bb11 : bb01;
    pa1.u[2] = hi2 ? cb10 : cb00;
    pa1.u[3] = hi2 ? cb11 : cb01;
    // ---- PV: one Gf read feeds both col-groups ----
    #pragma unroll
    for (int ct=0; ct<8; ++ct){
      int c = 16*ct + lr;
      int goff = 16384 + c*64 + ((16*lg) ^ (((c>>1)&3)<<4));
      bf16x8 Gf = *(const bf16x8*)(pb_ + goff);
      yacc0[ct] = MFMA(pa0.v, Gf, yacc0[ct]);
      yacc1[ct] = MFMA(pa1.v, Gf, yacc1[ct]);
    }
    __syncthreads();   // drains vmcnt (stage t+1) + lgkmcnt; buffers swap safely
    cur ^= 1;
  }
  // row sums per col-group
  float rs0 = psum0;
  rs0 += __shfl_xor(rs0, 16, 64); rs0 += __shfl_xor(rs0, 32, 64);
  float rs1 = psum1;
  rs1 += __shfl_xor(rs1, 16, 64); rs1 += __shfl_xor(rs1, 32, 64);
  float inv0 = 1.0f / rs0, inv1 = 1.0f / rs1;
  float ivr0[4], ivr1[4];
  #pragma unroll
  for (int r=0; r<4; ++r){
    ivr0[r] = __shfl(inv0, 4*lg + r, 64);
    ivr1[r] = __shfl(inv1, 4*lg + r, 64);
  }
  __bf16* yb0 = y + ((size_t)(b*N_ + n0 + 32*w))*CI_;
  __bf16* yb1 = y + ((size_t)(b*N_ + n0 + 32*w + 16))*CI_;
  #pragma unroll
  for (int ct=0; ct<8; ++ct){
    #pragma unroll
    for (int r=0;r<4;++r){
      yb0[(size_t)(4*lg+r)*CI_ + 16*ct + lr] = (__bf16)(yacc0[ct][r] * ivr0[r]);
      yb1[(size_t)(4*lg+r)*CI_ + 16*ct + lr] = (__bf16)(yacc1[ct][r] * ivr1[r]);
    }
  }
}

// ---------------- K4: z = zw @ y (2-term: y bf16, zw hi/lo); z bf16 + BN partials ----------------
__global__ __launch_bounds__(256,3) void k_zproj(const __bf16* __restrict__ y,
                        const __bf16* __restrict__ zwh, const __bf16* __restrict__ zwl,
                        __bf16* __restrict__ z, float* __restrict__ pS, float* __restrict__ pQ){
  __shared__ float zt[64][68];
  __shared__ float red[4][256][2];
  __shared__ char wbuf[2][8192];    // [hi 4KB | lo 4KB], 16 rows x 256B, swizzled
  int wg = blockIdx.x; int nt = wg % NT_; int b = wg/NT_; int n0 = nt*64;
  int tid = threadIdx.x; int w = tid>>6; int l = tid&63; int lr = l&15; int lg = l>>4;
  const __bf16* yb = y + ((size_t)(b*N_ + n0 + 16*w))*CI_ + (size_t)lr*CI_;
  bf16x8 Ay[4];
  #pragma unroll
  for (int ks=0;ks<4;++ks) Ay[ks] = *(const bf16x8*)(yb + 32*ks + 8*lg);
  int sp_part[2]; int sp_rowc[2]; int sp_off[2];
  #pragma unroll
  for (int i=0;i<2;++i){
    int p = i*4096 + tid*16;
    sp_part[i] = p>>12;
    int row = (p>>8)&15;
    int colb = p & 255;
    sp_rowc[i] = row*CI_ + ((colb ^ ((row&7)<<4)) >> 1);
    sp_off[i] = i*4096 + w*1024;
  }
  #pragma unroll
  for (int i=0;i<2;++i){
    const __bf16* src = (sp_part[i] ? zwl : zwh) + sp_rowc[i];
    gload_lds16(src, &wbuf[0][sp_off[i]]);
  }
  __syncthreads();

  __bf16* zb = z + (size_t)b*C_*N_ + n0;
  int cur = 0;
  for (int og=0; og<4; ++og){
    #pragma unroll
    for (int oi=0; oi<4; ++oi){
      int ot = og*4 + oi;
      if (ot < 15){
        #pragma unroll
        for (int i=0;i<2;++i){
          const __bf16* src = (sp_part[i] ? zwl : zwh) + (size_t)(16*(ot+1))*CI_ + sp_rowc[i];
          gload_lds16(src, &wbuf[cur^1][sp_off[i]]);
        }
      }
      const char* wb = wbuf[cur];
      f32x4 aHH = {0.f,0.f,0.f,0.f}, aHL = {0.f,0.f,0.f,0.f};
      int swz = (lr&7)<<4;
      #pragma unroll
      for (int ks=0;ks<4;++ks){
        int off = lr*256 + ((ks*64 + lg*16) ^ swz);
        bf16x8 Bh = *(const bf16x8*)(wb + off);
        bf16x8 Bl = *(const bf16x8*)(wb + 4096 + off);
        aHH = MFMA(Ay[ks], Bh, aHH);
        aHL = MFMA(Ay[ks], Bl, aHL);
      }
      f32x4 acc = aHH + aHL;
      float s1=0.f, s2=0.f;
      #pragma unroll
      for (int r=0;r<4;++r){
        float v = acc[r];
        int nl = 16*w + 4*lg + r;
        zt[16*oi+lr][nl] = v;
        s1 += v; s2 += v*v;
      }
      s1 += __shfl_xor(s1,16,64); s1 += __shfl_xor(s1,32,64);
      s2 += __shfl_xor(s2,16,64); s2 += __shfl_xor(s2,32,64);
      if (lg==0){ red[w][16*ot+lr][0] = s1; red[w][16*ot+lr][1] = s2; }
      if (oi < 3){ __syncthreads(); cur ^= 1; }
    }
    __syncthreads();
    #pragma unroll
    for (int it=0; it<2; ++it){
      int idx = it*256 + tid;
      int ol = idx>>3, cc = idx&7;
      f32x4 v0 = *(const f32x4*)(&zt[ol][cc*8]);
      f32x4 v1 = *(const f32x4*)(&zt[ol][cc*8+4]);
      bf16x8 o8;
      #pragma unroll
      for (int j=0;j<4;++j){ o8[j] = (__bf16)v0[j]; o8[4+j] = (__bf16)v1[j]; }
      *(bf16x8*)(zb + (size_t)(og*64 + ol)*N_ + cc*8) = o8;
    }
    __syncthreads();
    cur ^= 1;
  }
  float t1 = red[0][tid][0]+red[1][tid][0]+red[2][tid][0]+red[3][tid][0];
  float t2 = red[0][tid][1]+red[1][tid][1]+red[2][tid][1]+red[3][tid][1];
  pS[(size_t)wg*256 + tid] = t1;
  pQ[(size_t)wg*256 + tid] = t2;
}

// ---------------- K5: reduce partials -> per-channel scale/shift ----------------
__global__ __launch_bounds__(256) void k_stats(const float* __restrict__ pS, const float* __restrict__ pQ,
                        const float* __restrict__ gamma, const float* __restrict__ beta,
                        float* __restrict__ coef){
  int o = blockIdx.x; int t = threadIdx.x;
  float s=0.f, q=0.f;
  for (int i=t; i<NBLK_; i+=256){ s += pS[(size_t)i*256+o]; q += pQ[(size_t)i*256+o]; }
  __shared__ float rs[4], rq[4];
  #pragma unroll
  for (int sh=32; sh; sh>>=1){ s += __shfl_down(s,sh,64); q += __shfl_down(q,sh,64); }
  int w = t>>6;
  if ((t&63)==0){ rs[w]=s; rq[w]=q; }
  __syncthreads();
  if (t==0){
    s = rs[0]+rs[1]+rs[2]+rs[3]; q = rq[0]+rq[1]+rq[2]+rq[3];
    float inv = 1.0f/(float)(B_*N_);
    float mean = s*inv, var = q*inv - mean*mean;
    float a = gamma[o]*rsqrtf(var + 1e-5f);
    coef[o] = a; coef[256+o] = beta[o] - mean*a;
  }
}

// ---------------- K6: out = x + a_o*z + b_o  (z bf16) ----------------
__global__ __launch_bounds__(256) void k_final(const float* __restrict__ x, const __bf16* __restrict__ z,
                        const float* __restrict__ coef, float* __restrict__ out){
  uint32_t i = blockIdx.x*256 + threadIdx.x;
  uint32_t e0 = i*8u;
  if (e0 >= (uint32_t)(B_*C_*N_)) return;
  int o = (int)((e0 / (uint32_t)N_) % (uint32_t)C_);
  float a = coef[o], b2 = coef[256+o];
  bf16x8 zv = *(const bf16x8*)(z + e0);
  f32x4 x0 = *(const f32x4*)(x + e0);
  f32x4 x1 = *(const f32x4*)(x + e0 + 4);
  f32x4 r0, r1;
  #pragma unroll
  for (int j=0;j<4;++j){
    r0[j] = x0[j] + (float)zv[j]*a + b2;
    r1[j] = x1[j] + (float)zv[4+j]*a + b2;
  }
  *(f32x4*)(out + e0) = r0;
  *(f32x4*)(out + e0 + 4) = r1;
}

extern "C" void kernel_launch(void* const* d_in, const int* in_sizes, int n_in,
                              void* d_out, int out_size, void* d_ws, size_t ws_size,
                              hipStream_t stream){
  const float* x     = (const float*)d_in[0];
  const float* wt    = (const float*)d_in[1];
  const float* wp    = (const float*)d_in[2];
  const float* wg    = (const float*)d_in[3];
  const float* zw    = (const float*)d_in[4];
  const float* gamma = (const float*)d_in[5];
  const float* beta  = (const float*)d_in[6];
  float* out = (float*)d_out;
  char* ws = (char*)d_ws;
  size_t off = 0;
  auto alloc = [&](size_t bytes)->void*{ void* p = ws + off; off = (off + bytes + 255) & ~(size_t)255; return p; };
  __bf16* y    = (__bf16*)alloc((size_t)B_*N_*CI_*2);     // 12.85 MB (written by k_attn, bf16)
  float*  phf32= (float*)alloc((size_t)B_*N_*CI_*4);      // 25.7 MB; z (bf16 12.85MB) aliases this
  __bf16* ggf  = (__bf16*)alloc((size_t)B_*N_*CI_*2);     // 12.85 MB
  __bf16* th_hi= (__bf16*)alloc((size_t)B_*N_*CI_*2);     // 12.85 MB
  __bf16* th_lo= (__bf16*)alloc((size_t)B_*N_*CI_*2);     // 12.85 MB
  __bf16* wth  = (__bf16*)alloc(32768*2);
  __bf16* wtl  = (__bf16*)alloc(32768*2);
  __bf16* wph  = (__bf16*)alloc(32768*2);
  __bf16* wpl  = (__bf16*)alloc(32768*2);
  __bf16* wgh  = (__bf16*)alloc(32768*2);
  __bf16* wgl  = (__bf16*)alloc(32768*2);
  __bf16* zwh  = (__bf16*)alloc(32768*2);
  __bf16* zwl  = (__bf16*)alloc(32768*2);
  __bf16* phph = (__bf16*)alloc((size_t)B_*NP2_*CI_*2);   // 1.64 MB
  __bf16* phpl = (__bf16*)alloc((size_t)B_*NP2_*CI_*2);   // 1.64 MB
  __bf16* ggp  = (__bf16*)alloc((size_t)B_*CI_*NP2_*2);   // 1.64 MB
  float*  pS   = (float*)alloc((size_t)NBLK_*256*4);
  float*  pQ   = (float*)alloc((size_t)NBLK_*256*4);
  float*  coef = (float*)alloc(512*4);
  float*  phmean = (float*)alloc(B_*CI_*4);
  float*  pph  = (float*)alloc((size_t)400*128*4);
  __bf16* z = (__bf16*)phf32;      // z (bf16 12.85MB) reuses phf32 (dead after k_pool)

  k_wconv<<<128, 256, 0, stream>>>(wt, wp, wg, zw, wth, wtl, wph, wpl, wgh, wgl, zwh, zwl);
  k_proj3<<<NBLK_, 256, 0, stream>>>(x, wth, wtl, wph, wpl, wgh, wgl, th_hi, th_lo, phf32, ggf);
  k_pool<<<400, 256, 0, stream>>>(phf32, ggf, phph, phpl, ggp, pph);
  k_phmean2<<<2, 256, 0, stream>>>(pph, phmean);
  k_attn<<<NBLK2_, 256, 0, stream>>>(th_hi, th_lo, phph, phpl, ggp, phmean, y);
  k_zproj<<<NBLK_, 256, 0, stream>>>(y, zwh, zwl, z, pS, pQ);
  k_stats<<<256, 256, 0, stream>>>(pS, pQ, gamma, beta, coef);
  k_final<<<(B_*C_*N_/8 + 255)/256, 256, 0, stream>>>(x, z, coef, out);
}

// Round 20
// 216.905 us; speedup vs baseline: 1.0469x; 1.0469x over previous
//
#include <hip/hip_runtime.h>
#include <stdint.h>

// ---- problem constants (fixed by setup_inputs) ----
#define B_   4
#define C_   256
#define CI_  128
#define T_   16
#define H_   28
#define W_   28
#define HW_  784          // H*W
#define N_   12544        // T*H*W
#define TP_  8
#define HP_  14
#define WP_  14
#define NP_  1568         // pooled positions = 49*32 exactly
#define NP2_ 1600         // padded to 25*64 (pool/g layout only)
#define NT_  196          // N/64  (64-row kernels)
#define NT2_ 98           // N/128 (k_attn 128-query blocks)
#define NBLK_ 784         // B*NT
#define NBLK2_ 392        // B*NT2
#define KVB_ 32           // key tile for k_attn
#define NKT_ 49           // NP_/KVB_
#define LOG2E_ 1.4426950408889634f

typedef __attribute__((ext_vector_type(8))) __bf16 bf16x8;
typedef __attribute__((ext_vector_type(4))) float  f32x4;

#define MFMA(a,b,c) __builtin_amdgcn_mfma_f32_16x16x32_bf16(a,b,c,0,0,0)
#define EXP2(x) __builtin_amdgcn_exp2f(x)

__device__ __forceinline__ void split_bf16(float f, __bf16& hi, __bf16& lo){
  hi = (__bf16)f;
  lo = (__bf16)(f - (float)hi);
}

__device__ __forceinline__ uint32_t pack2(float a, float b){
  union { __bf16 h; unsigned short s; } ua, ub;
  ua.h = (__bf16)a; ub.h = (__bf16)b;
  return (uint32_t)ua.s | ((uint32_t)ub.s << 16);
}

__device__ __forceinline__ void gload_lds16(const void* g, void* l){
  __builtin_amdgcn_global_load_lds((const __attribute__((address_space(1))) void*)g,
                                   (__attribute__((address_space(3))) void*)l, 16, 0, 0);
}

// ---------------- K0w: split weights fp32 -> bf16 hi/lo ----------------
__global__ __launch_bounds__(256) void k_wconv(const float* __restrict__ wt, const float* __restrict__ wp,
                       const float* __restrict__ wg, const float* __restrict__ zw,
                       __bf16* __restrict__ wth, __bf16* __restrict__ wtl,
                       __bf16* __restrict__ wph, __bf16* __restrict__ wpl,
                       __bf16* __restrict__ wgh, __bf16* __restrict__ wgl,
                       __bf16* __restrict__ zwh, __bf16* __restrict__ zwl){
  int i = blockIdx.x*256 + threadIdx.x;
  if (i < 32768){
    __bf16 h, lo;
    split_bf16(wt[i], h, lo); wth[i]=h; wtl[i]=lo;
    split_bf16(wp[i], h, lo); wph[i]=h; wpl[i]=lo;
    split_bf16(wg[i], h, lo); wgh[i]=h; wgl[i]=lo;
    split_bf16(zw[i], h, lo); zwh[i]=h; zwl[i]=lo;
  }
}

// ---------------- K1: projections; x read DIRECT (fp32, strided) + on-the-fly split ----------------
// theta stored pre-scaled by log2e (exact exp2 substitution in k_attn).
// g projection 2-term (x_hi*w_lo dropped: ~0.001 abs, << g bf16 rounding).
__global__ __launch_bounds__(256,4) void k_proj3(const float* __restrict__ x,
                        const __bf16* __restrict__ wth, const __bf16* __restrict__ wtl,
                        const __bf16* __restrict__ wph, const __bf16* __restrict__ wpl,
                        const __bf16* __restrict__ wgh, const __bf16* __restrict__ wgl,
                        __bf16* __restrict__ th_hi, __bf16* __restrict__ th_lo,
                        float* __restrict__ phf32, __bf16* __restrict__ ggf){
  __shared__ char wbuf[2][16384];   // [hi 8KB | lo 8KB], 16 rows x 512B, swizzled
  int wg = blockIdx.x;
  int nt = wg % NT_; int b = wg/NT_;
  int n0 = nt*64;
  int tid = threadIdx.x; int w = tid>>6; int l = tid&63; int lr = l&15; int lg = l>>4;
  int nrow = 16*w + lr;
  const float* xb = x + (size_t)b*C_*N_ + (n0 + nrow);
  bf16x8 Ah[8], Al[8];
  #pragma unroll
  for (int ks=0; ks<8; ++ks){
    #pragma unroll
    for (int j=0;j<8;++j){
      float v = xb[(size_t)(32*ks + 8*lg + j)*N_];
      __bf16 hi, lo; split_bf16(v, hi, lo);
      Ah[ks][j] = hi; Al[ks][j] = lo;
    }
  }
  int sp_part[4]; int sp_rowc[4]; int sp_off[4];
  #pragma unroll
  for (int i=0;i<4;++i){
    int p = i*4096 + tid*16;
    sp_part[i] = p>>13;                       // 0 hi, 1 lo
    int row = (p>>9)&15;
    int colb = p & 511;
    sp_rowc[i] = row*C_ + ((colb ^ ((row&7)<<4)) >> 1);
    sp_off[i] = i*4096 + w*1024;
  }
  #pragma unroll
  for (int i=0;i<4;++i){
    const __bf16* src = (sp_part[i] ? wtl : wth) + sp_rowc[i];
    gload_lds16(src, &wbuf[0][sp_off[i]]);
  }
  __syncthreads();

  size_t obase = ((size_t)(b*N_ + n0))*CI_;
  int cur = 0;
  for (int pair=0; pair<24; ++pair){
    int p = pair>>3, ot = pair&7;
    if (pair < 23){
      int pn = pair+1, p2 = pn>>3, ot2 = pn&7;
      const __bf16* bh = (p2==0) ? wth : ((p2==1) ? wph : wgh);
      const __bf16* bl = (p2==0) ? wtl : ((p2==1) ? wpl : wgl);
      #pragma unroll
      for (int i=0;i<4;++i){
        const __bf16* src = (sp_part[i] ? bl : bh) + (size_t)(16*ot2)*C_ + sp_rowc[i];
        gload_lds16(src, &wbuf[cur^1][sp_off[i]]);
      }
    }
    const char* wb = wbuf[cur];
    f32x4 aHH={0.f,0.f,0.f,0.f}, aLH={0.f,0.f,0.f,0.f}, aHL={0.f,0.f,0.f,0.f};
    int swz = (lr&7)<<4;
    if (p < 2){
      #pragma unroll
      for (int ks=0; ks<8; ++ks){
        int off = lr*512 + ((ks*64 + lg*16) ^ swz);
        bf16x8 Bh = *(const bf16x8*)(wb + off);
        bf16x8 Bl = *(const bf16x8*)(wb + 8192 + off);
        aHH = MFMA(Ah[ks], Bh, aHH);
        aLH = MFMA(Al[ks], Bh, aLH);
        aHL = MFMA(Ah[ks], Bl, aHL);
      }
    } else {
      #pragma unroll
      for (int ks=0; ks<8; ++ks){
        int off = lr*512 + ((ks*64 + lg*16) ^ swz);
        bf16x8 Bh = *(const bf16x8*)(wb + off);
        aHH = MFMA(Ah[ks], Bh, aHH);
        aLH = MFMA(Al[ks], Bh, aLH);
      }
    }
    f32x4 acc = aHH + aLH + aHL;
    if (p == 0){
      #pragma unroll
      for (int r=0;r<4;++r){
        int n = 16*w + 4*lg + r;
        float sv = acc[r] * LOG2E_;
        __bf16 hi, lo; split_bf16(sv, hi, lo);
        th_hi[obase + (size_t)n*CI_ + 16*ot + lr] = hi;
        th_lo[obase + (size_t)n*CI_ + 16*ot + lr] = lo;
      }
    } else if (p == 1){
      #pragma unroll
      for (int r=0;r<4;++r){
        int n = 16*w + 4*lg + r;
        phf32[obase + (size_t)n*CI_ + 16*ot + lr] = acc[r];
      }
    } else {
      #pragma unroll
      for (int r=0;r<4;++r){
        int n = 16*w + 4*lg + r;
        ggf[obase + (size_t)n*CI_ + 16*ot + lr] = (__bf16)acc[r];
      }
    }
    __syncthreads();
    cur ^= 1;
  }
}

// ---------------- K2: maxpool + fused phmean partials ----------------
__global__ __launch_bounds__(256) void k_pool(const float* __restrict__ phf32, const __bf16* __restrict__ ggf,
                       __bf16* __restrict__ phph, __bf16* __restrict__ phpl,
                       __bf16* __restrict__ ggp, float* __restrict__ pph){
  __shared__ float red[16][128];
  int blk = blockIdx.x;            // 400 = B * 100
  int tid = threadIdx.x;
  int idx = blk*256 + tid;
  int c8 = idx & 15;
  int m  = (idx>>4) % NP2_;
  int b  = idx / (16*NP2_);
  bool valid = (m < NP_);
  float mp[8], mg[8];
  #pragma unroll
  for (int j=0;j<8;++j){ mp[j] = 0.f; mg[j] = 0.f; }
  if (valid){
    #pragma unroll
    for (int j=0;j<8;++j){ mp[j] = -3e38f; mg[j] = -3e38f; }
    int tp = m/(HP_*WP_), hp = (m/WP_)%HP_, wq = m%WP_;
    int t0 = tp*2, h0 = hp*2, w0 = wq*2;
    const float*  pb = phf32 + ((size_t)b*N_)*CI_ + c8*8;
    const __bf16* gb = ggf   + ((size_t)b*N_)*CI_ + c8*8;
    #pragma unroll
    for (int dt=0; dt<2; ++dt)
    #pragma unroll
    for (int dh=0; dh<2; ++dh)
    #pragma unroll
    for (int dw=0; dw<2; ++dw){
      int n = (t0+dt)*HW_ + (h0+dh)*W_ + (w0+dw);
      f32x4 p0 = *(const f32x4*)(pb + (size_t)n*CI_);
      f32x4 p1 = *(const f32x4*)(pb + (size_t)n*CI_ + 4);
      bf16x8 vg = *(const bf16x8*)(gb + (size_t)n*CI_);
      #pragma unroll
      for (int j=0;j<4;++j){ mp[j] = fmaxf(mp[j], p0[j]); mp[4+j] = fmaxf(mp[4+j], p1[j]); }
      #pragma unroll
      for (int j=0;j<8;++j){ mg[j] = fmaxf(mg[j], (float)vg[j]); }
    }
  }
  bf16x8 oh, ol, og;
  #pragma unroll
  for (int j=0;j<8;++j){
    __bf16 hi, lo;
    split_bf16(mp[j], hi, lo);
    oh[j] = hi; ol[j] = lo;
    og[j] = (__bf16)mg[j];
  }
  *(bf16x8*)(phph + ((size_t)(b*NP2_ + m))*CI_ + c8*8) = oh;
  *(bf16x8*)(phpl + ((size_t)(b*NP2_ + m))*CI_ + c8*8) = ol;
  #pragma unroll
  for (int j=0;j<8;++j) ggp[((size_t)(b*CI_ + c8*8 + j))*NP2_ + m] = og[j];
  // fused phmean partial: sum over this block's 16 m values
  int ms = tid >> 4;
  #pragma unroll
  for (int j=0;j<8;++j) red[ms][c8*8 + j] = mp[j];
  __syncthreads();
  if (tid < 128){
    float s = 0.f;
    #pragma unroll
    for (int k=0;k<16;++k) s += red[k][tid];
    pph[(size_t)blk*128 + tid] = s;
  }
}

// ---------------- K2b: reduce pph[400][128] -> phmean[b][c] ----------------
__global__ __launch_bounds__(256) void k_phmean2(const float* __restrict__ pph, float* __restrict__ phmean){
  int t = blockIdx.x*256 + threadIdx.x;
  if (t >= B_*CI_) return;
  int b = t >> 7, c = t & 127;
  float s = 0.f;
  for (int k=0; k<100; ++k) s += pph[(size_t)(b*100+k)*128 + c];
  phmean[b*CI_ + c] = s * (1.0f/(float)NP_);
}

// ---------------- K3: attention; 4 waves x 32 query-cols (2 col-groups); native exp2; y bf16 ----------------
// (256,2): VGPR+AGPR ~216 needs cap 256 -> no spill (verified r15/r17).
__global__ __launch_bounds__(256,2) void k_attn(const __bf16* __restrict__ th_hi, const __bf16* __restrict__ th_lo,
                       const __bf16* __restrict__ phph, const __bf16* __restrict__ phpl,
                       const __bf16* __restrict__ ggp, const float* __restrict__ phmean,
                       __bf16* __restrict__ y){
  __shared__ char sbuf[2][24576];   // [phiH 8KB | phiL 8KB | g 8KB]
  __shared__ float estp[128][2];
  __shared__ float est[128];
  int wg = blockIdx.x;
  int nt = wg % NT2_; int b = wg/NT2_;
  int n0 = nt*128;
  int tid = threadIdx.x; int w = tid>>6; int l = tid&63; int lr = l&15; int lg = l>>4;
  const __bf16* phb = phph + (size_t)b*NP2_*CI_;
  const __bf16* plb = phpl + (size_t)b*NP2_*CI_;
  const __bf16* ggb = ggp + (size_t)b*CI_*NP2_;

  // --- est[row] = theta'(n0+row) . phmean[b]  (theta' pre-scaled by log2e) ---
  {
    int row = tid >> 1, q = tid & 1;
    const __bf16* rh = th_hi + ((size_t)(b*N_ + n0 + row))*CI_ + 64*q;
    const __bf16* rl = th_lo + ((size_t)(b*N_ + n0 + row))*CI_ + 64*q;
    const float* pm = phmean + b*CI_ + 64*q;
    float sacc = 0.f;
    #pragma unroll
    for (int j=0;j<8;++j){
      bf16x8 vh = *(const bf16x8*)(rh + 8*j);
      bf16x8 vl = *(const bf16x8*)(rl + 8*j);
      f32x4 p0 = *(const f32x4*)(pm + 8*j);
      f32x4 p1 = *(const f32x4*)(pm + 8*j + 4);
      #pragma unroll
      for (int k=0;k<4;++k){
        sacc += ((float)vh[k]   + (float)vl[k]  )*p0[k];
        sacc += ((float)vh[4+k] + (float)vl[4+k])*p1[k];
      }
    }
    estp[row][q] = sacc;
  }
  // --- staging descriptors: 6 global_load_lds per wave per tile (4 waves x 6 = 24) ---
  const __bf16* sptr[6]; int sstr[6]; int soff[6];
  #pragma unroll
  for (int jj=0; jj<6; ++jj){
    int j = w*6 + jj;              // 0..23
    int p = j*1024 + l*16;         // byte within 24KB tile
    int reg = p >> 13;             // 0 phiH, 1 phiL, 2 g
    int e = p & 8191;
    if (reg < 2){
      int m = e >> 8;
      int chb = (e & 255) ^ ((m & 7) << 4);
      const __bf16* base = (reg==0 ? phb : plb);
      sptr[jj] = base + (size_t)m*CI_ + (chb>>1);
      sstr[jj] = KVB_*CI_;
    } else {
      int c = e >> 6;
      int chb = (e & 63) ^ (((c >> 1) & 3) << 4);   // decorrelated swizzle (matches read)
      sptr[jj] = ggb + (size_t)c*NP2_ + (chb>>1);
      sstr[jj] = KVB_;
    }
    soff[jj] = j*1024;             // wave-uniform LDS base (HW adds lane*16)
  }
  __syncthreads();
  if (tid < 128) est[tid] = estp[tid][0]+estp[tid][1];

  // theta fragments for 2 col-groups: cols n0 + 32w + 16cg + lr
  bf16x8 Ah[2][4], Al[2][4];
  #pragma unroll
  for (int cg=0; cg<2; ++cg){
    size_t tb = ((size_t)(b*N_ + n0 + 32*w + 16*cg))*CI_ + (size_t)lr*CI_;
    #pragma unroll
    for (int ks=0; ks<4; ++ks){
      Ah[cg][ks] = *(const bf16x8*)(th_hi + tb + 32*ks + 8*lg);
      Al[cg][ks] = *(const bf16x8*)(th_lo + tb + 32*ks + 8*lg);
    }
  }
  f32x4 yacc0[8], yacc1[8];
  #pragma unroll
  for (int ct=0; ct<8; ++ct){ yacc0[ct] = (f32x4){0.f,0.f,0.f,0.f}; yacc1[ct] = (f32x4){0.f,0.f,0.f,0.f}; }
  float psum0 = 0.f, psum1 = 0.f;
  __syncthreads();
  float estl0 = est[32*w + lr];
  float estl1 = est[32*w + 16 + lr];

  // prologue: stage tile 0
  #pragma unroll
  for (int jj=0; jj<6; ++jj) gload_lds16(sptr[jj], &sbuf[0][soff[jj]]);
  __syncthreads();

  int s1 = lr + (((2*lg)  )&3)*16;   // source lanes for PA assembly
  int s2 = lr + (((2*lg+1))&3)*16;
  bool hi2 = (lg >= 2);

  int cur = 0;
  for (int t=0; t<NKT_; ++t){
    if (t < NKT_-1){
      #pragma unroll
      for (int jj=0; jj<6; ++jj)
        gload_lds16(sptr[jj] + (size_t)(t+1)*sstr[jj], &sbuf[cur^1][soff[jj]]);
    }
    const char* pb_ = sbuf[cur];
    // ---- swapped QK (3-term), both col-groups share phi fragment reads ----
    uint32_t qa00, qa01, qa10, qa11, qb00, qb01, qb10, qb11;
    #pragma unroll
    for (int mt=0; mt<2; ++mt){
      f32x4 aHH0={0.f,0.f,0.f,0.f}, aLH0={0.f,0.f,0.f,0.f}, aHL0={0.f,0.f,0.f,0.f};
      f32x4 aHH1={0.f,0.f,0.f,0.f}, aLH1={0.f,0.f,0.f,0.f}, aHL1={0.f,0.f,0.f,0.f};
      int mrow = 16*mt + lr;
      int swz = (mrow&7)<<4;
      #pragma unroll
      for (int ks=0; ks<4; ++ks){
        int off = mrow*256 + ((64*ks + 16*lg) ^ swz);
        bf16x8 Bh = *(const bf16x8*)(pb_ + off);
        bf16x8 Bl = *(const bf16x8*)(pb_ + 8192 + off);
        aHH0 = MFMA(Bh, Ah[0][ks], aHH0);
        aLH0 = MFMA(Bh, Al[0][ks], aLH0);
        aHL0 = MFMA(Bl, Ah[0][ks], aHL0);
        aHH1 = MFMA(Bh, Ah[1][ks], aHH1);
        aLH1 = MFMA(Bh, Al[1][ks], aLH1);
        aHL1 = MFMA(Bl, Ah[1][ks], aHL1);
      }
      f32x4 sv0 = aHH0 + aLH0 + aHL0;
      f32x4 sv1 = aHH1 + aLH1 + aHL1;
      float p00 = EXP2(sv0[0]-estl0), p01 = EXP2(sv0[1]-estl0);
      float p02 = EXP2(sv0[2]-estl0), p03 = EXP2(sv0[3]-estl0);
      float p10 = EXP2(sv1[0]-estl1), p11 = EXP2(sv1[1]-estl1);
      float p12 = EXP2(sv1[2]-estl1), p13 = EXP2(sv1[3]-estl1);
      psum0 += (p00 + p01) + (p02 + p03);
      psum1 += (p10 + p11) + (p12 + p13);
      uint32_t da0 = pack2(p00,p01), da1 = pack2(p02,p03);
      uint32_t db0 = pack2(p10,p11), db1 = pack2(p12,p13);
      if (mt == 0){ qa00 = da0; qa01 = da1; qb00 = db0; qb01 = db1; }
      else        { qa10 = da0; qa11 = da1; qb10 = db0; qb11 = db1; }
    }
    // ---- assemble PA for each col-group ----
    uint32_t ba00 = __shfl(qa00, s1, 64), ba10 = __shfl(qa10, s1, 64);
    uint32_t ba01 = __shfl(qa01, s1, 64), ba11 = __shfl(qa11, s1, 64);
    uint32_t ca00 = __shfl(qa00, s2, 64), ca10 = __shfl(qa10, s2, 64);
    uint32_t ca01 = __shfl(qa01, s2, 64), ca11 = __shfl(qa11, s2, 64);
    union { uint32_t u[4]; bf16x8 v; } pa0;
    pa0.u[0] = hi2 ? ba10 : ba00;
    pa0.u[1] = hi2 ? ba11 : ba01;
    pa0.u[2] = hi2 ? ca10 : ca00;
    pa0.u[3] = hi2 ? ca11 : ca01;
    uint32_t bb00 = __shfl(qb00, s1, 64), bb10 = __shfl(qb10, s1, 64);
    uint32_t bb01 = __shfl(qb01, s1, 64), bb11 = __shfl(qb11, s1, 64);
    uint32_t cb00 = __shfl(qb00, s2, 64), cb10 = __shfl(qb10, s2, 64);
    uint32_t cb01 = __shfl(qb01, s2, 64), cb11 = __shfl(qb11, s2, 64);
    union { uint32_t u[4]; bf16x8 v; } pa1;
    pa1.u[0] = hi2 ? bb10 : bb00;
    pa1.u[1] = hi2 ? bb11 : bb01;
    pa1.u[2] = hi2 ? cb10 : cb00;
    pa1.u[3] = hi2 ? cb11 : cb01;
    // ---- PV: one Gf read feeds both col-groups ----
    #pragma unroll
    for (int ct=0; ct<8; ++ct){
      int c = 16*ct + lr;
      int goff = 16384 + c*64 + ((16*lg) ^ (((c>>1)&3)<<4));
      bf16x8 Gf = *(const bf16x8*)(pb_ + goff);
      yacc0[ct] = MFMA(pa0.v, Gf, yacc0[ct]);
      yacc1[ct] = MFMA(pa1.v, Gf, yacc1[ct]);
    }
    __syncthreads();   // drains vmcnt (stage t+1) + lgkmcnt; buffers swap safely
    cur ^= 1;
  }
  // row sums per col-group
  float rs0 = psum0;
  rs0 += __shfl_xor(rs0, 16, 64); rs0 += __shfl_xor(rs0, 32, 64);
  float rs1 = psum1;
  rs1 += __shfl_xor(rs1, 16, 64); rs1 += __shfl_xor(rs1, 32, 64);
  float inv0 = 1.0f / rs0, inv1 = 1.0f / rs1;
  float ivr0[4], ivr1[4];
  #pragma unroll
  for (int r=0; r<4; ++r){
    ivr0[r] = __shfl(inv0, 4*lg + r, 64);
    ivr1[r] = __shfl(inv1, 4*lg + r, 64);
  }
  __bf16* yb0 = y + ((size_t)(b*N_ + n0 + 32*w))*CI_;
  __bf16* yb1 = y + ((size_t)(b*N_ + n0 + 32*w + 16))*CI_;
  #pragma unroll
  for (int ct=0; ct<8; ++ct){
    #pragma unroll
    for (int r=0;r<4;++r){
      yb0[(size_t)(4*lg+r)*CI_ + 16*ct + lr] = (__bf16)(yacc0[ct][r] * ivr0[r]);
      yb1[(size_t)(4*lg+r)*CI_ + 16*ct + lr] = (__bf16)(yacc1[ct][r] * ivr1[r]);
    }
  }
}

// ---------------- K4: z = zw @ y (2-term: y bf16, zw hi/lo); z bf16 + BN partials ----------------
__global__ __launch_bounds__(256,3) void k_zproj(const __bf16* __restrict__ y,
                        const __bf16* __restrict__ zwh, const __bf16* __restrict__ zwl,
                        __bf16* __restrict__ z, float* __restrict__ pS, float* __restrict__ pQ){
  __shared__ float zt[64][68];
  __shared__ float red[4][256][2];
  __shared__ char wbuf[2][8192];    // [hi 4KB | lo 4KB], 16 rows x 256B, swizzled
  int wg = blockIdx.x; int nt = wg % NT_; int b = wg/NT_; int n0 = nt*64;
  int tid = threadIdx.x; int w = tid>>6; int l = tid&63; int lr = l&15; int lg = l>>4;
  const __bf16* yb = y + ((size_t)(b*N_ + n0 + 16*w))*CI_ + (size_t)lr*CI_;
  bf16x8 Ay[4];
  #pragma unroll
  for (int ks=0;ks<4;++ks) Ay[ks] = *(const bf16x8*)(yb + 32*ks + 8*lg);
  int sp_part[2]; int sp_rowc[2]; int sp_off[2];
  #pragma unroll
  for (int i=0;i<2;++i){
    int p = i*4096 + tid*16;
    sp_part[i] = p>>12;
    int row = (p>>8)&15;
    int colb = p & 255;
    sp_rowc[i] = row*CI_ + ((colb ^ ((row&7)<<4)) >> 1);
    sp_off[i] = i*4096 + w*1024;
  }
  #pragma unroll
  for (int i=0;i<2;++i){
    const __bf16* src = (sp_part[i] ? zwl : zwh) + sp_rowc[i];
    gload_lds16(src, &wbuf[0][sp_off[i]]);
  }
  __syncthreads();

  __bf16* zb = z + (size_t)b*C_*N_ + n0;
  int cur = 0;
  for (int og=0; og<4; ++og){
    #pragma unroll
    for (int oi=0; oi<4; ++oi){
      int ot = og*4 + oi;
      if (ot < 15){
        #pragma unroll
        for (int i=0;i<2;++i){
          const __bf16* src = (sp_part[i] ? zwl : zwh) + (size_t)(16*(ot+1))*CI_ + sp_rowc[i];
          gload_lds16(src, &wbuf[cur^1][sp_off[i]]);
        }
      }
      const char* wb = wbuf[cur];
      f32x4 aHH = {0.f,0.f,0.f,0.f}, aHL = {0.f,0.f,0.f,0.f};
      int swz = (lr&7)<<4;
      #pragma unroll
      for (int ks=0;ks<4;++ks){
        int off = lr*256 + ((ks*64 + lg*16) ^ swz);
        bf16x8 Bh = *(const bf16x8*)(wb + off);
        bf16x8 Bl = *(const bf16x8*)(wb + 4096 + off);
        aHH = MFMA(Ay[ks], Bh, aHH);
        aHL = MFMA(Ay[ks], Bl, aHL);
      }
      f32x4 acc = aHH + aHL;
      float s1=0.f, s2=0.f;
      #pragma unroll
      for (int r=0;r<4;++r){
        float v = acc[r];
        int nl = 16*w + 4*lg + r;
        zt[16*oi+lr][nl] = v;
        s1 += v; s2 += v*v;
      }
      s1 += __shfl_xor(s1,16,64); s1 += __shfl_xor(s1,32,64);
      s2 += __shfl_xor(s2,16,64); s2 += __shfl_xor(s2,32,64);
      if (lg==0){ red[w][16*ot+lr][0] = s1; red[w][16*ot+lr][1] = s2; }
      if (oi < 3){ __syncthreads(); cur ^= 1; }
    }
    __syncthreads();
    #pragma unroll
    for (int it=0; it<2; ++it){
      int idx = it*256 + tid;
      int ol = idx>>3, cc = idx&7;
      f32x4 v0 = *(const f32x4*)(&zt[ol][cc*8]);
      f32x4 v1 = *(const f32x4*)(&zt[ol][cc*8+4]);
      bf16x8 o8;
      #pragma unroll
      for (int j=0;j<4;++j){ o8[j] = (__bf16)v0[j]; o8[4+j] = (__bf16)v1[j]; }
      *(bf16x8*)(zb + (size_t)(og*64 + ol)*N_ + cc*8) = o8;
    }
    __syncthreads();
    cur ^= 1;
  }
  float t1 = red[0][tid][0]+red[1][tid][0]+red[2][tid][0]+red[3][tid][0];
  float t2 = red[0][tid][1]+red[1][tid][1]+red[2][tid][1]+red[3][tid][1];
  pS[(size_t)wg*256 + tid] = t1;
  pQ[(size_t)wg*256 + tid] = t2;
}

// ---------------- K5: reduce partials -> per-channel scale/shift ----------------
__global__ __launch_bounds__(256) void k_stats(const float* __restrict__ pS, const float* __restrict__ pQ,
                        const float* __restrict__ gamma, const float* __restrict__ beta,
                        float* __restrict__ coef){
  int o = blockIdx.x; int t = threadIdx.x;
  float s=0.f, q=0.f;
  for (int i=t; i<NBLK_; i+=256){ s += pS[(size_t)i*256+o]; q += pQ[(size_t)i*256+o]; }
  __shared__ float rs[4], rq[4];
  #pragma unroll
  for (int sh=32; sh; sh>>=1){ s += __shfl_down(s,sh,64); q += __shfl_down(q,sh,64); }
  int w = t>>6;
  if ((t&63)==0){ rs[w]=s; rq[w]=q; }
  __syncthreads();
  if (t==0){
    s = rs[0]+rs[1]+rs[2]+rs[3]; q = rq[0]+rq[1]+rq[2]+rq[3];
    float inv = 1.0f/(float)(B_*N_);
    float mean = s*inv, var = q*inv - mean*mean;
    float a = gamma[o]*rsqrtf(var + 1e-5f);
    coef[o] = a; coef[256+o] = beta[o] - mean*a;
  }
}

// ---------------- K6: out = x + a_o*z + b_o  (z bf16) ----------------
__global__ __launch_bounds__(256) void k_final(const float* __restrict__ x, const __bf16* __restrict__ z,
                        const float* __restrict__ coef, float* __restrict__ out){
  uint32_t i = blockIdx.x*256 + threadIdx.x;
  uint32_t e0 = i*8u;
  if (e0 >= (uint32_t)(B_*C_*N_)) return;
  int o = (int)((e0 / (uint32_t)N_) % (uint32_t)C_);
  float a = coef[o], b2 = coef[256+o];
  bf16x8 zv = *(const bf16x8*)(z + e0);
  f32x4 x0 = *(const f32x4*)(x + e0);
  f32x4 x1 = *(const f32x4*)(x + e0 + 4);
  f32x4 r0, r1;
  #pragma unroll
  for (int j=0;j<4;++j){
    r0[j] = x0[j] + (float)zv[j]*a + b2;
    r1[j] = x1[j] + (float)zv[4+j]*a + b2;
  }
  *(f32x4*)(out + e0) = r0;
  *(f32x4*)(out + e0 + 4) = r1;
}

extern "C" void kernel_launch(void* const* d_in, const int* in_sizes, int n_in,
                              void* d_out, int out_size, void* d_ws, size_t ws_size,
                              hipStream_t stream){
  const float* x     = (const float*)d_in[0];
  const float* wt    = (const float*)d_in[1];
  const float* wp    = (const float*)d_in[2];
  const float* wg    = (const float*)d_in[3];
  const float* zw    = (const float*)d_in[4];
  const float* gamma = (const float*)d_in[5];
  const float* beta  = (const float*)d_in[6];
  float* out = (float*)d_out;
  char* ws = (char*)d_ws;
  size_t off = 0;
  auto alloc = [&](size_t bytes)->void*{ void* p = ws + off; off = (off + bytes + 255) & ~(size_t)255; return p; };
  __bf16* y    = (__bf16*)alloc((size_t)B_*N_*CI_*2);     // 12.85 MB (written by k_attn, bf16)
  float*  phf32= (float*)alloc((size_t)B_*N_*CI_*4);      // 25.7 MB; z (bf16 12.85MB) aliases this
  __bf16* ggf  = (__bf16*)alloc((size_t)B_*N_*CI_*2);     // 12.85 MB
  __bf16* th_hi= (__bf16*)alloc((size_t)B_*N_*CI_*2);     // 12.85 MB
  __bf16* th_lo= (__bf16*)alloc((size_t)B_*N_*CI_*2);     // 12.85 MB
  __bf16* wth  = (__bf16*)alloc(32768*2);
  __bf16* wtl  = (__bf16*)alloc(32768*2);
  __bf16* wph  = (__bf16*)alloc(32768*2);
  __bf16* wpl  = (__bf16*)alloc(32768*2);
  __bf16* wgh  = (__bf16*)alloc(32768*2);
  __bf16* wgl  = (__bf16*)alloc(32768*2);
  __bf16* zwh  = (__bf16*)alloc(32768*2);
  __bf16* zwl  = (__bf16*)alloc(32768*2);
  __bf16* phph = (__bf16*)alloc((size_t)B_*NP2_*CI_*2);   // 1.64 MB
  __bf16* phpl = (__bf16*)alloc((size_t)B_*NP2_*CI_*2);   // 1.64 MB
  __bf16* ggp  = (__bf16*)alloc((size_t)B_*CI_*NP2_*2);   // 1.64 MB
  float*  pS   = (float*)alloc((size_t)NBLK_*256*4);
  float*  pQ   = (float*)alloc((size_t)NBLK_*256*4);
  float*  coef = (float*)alloc(512*4);
  float*  phmean = (float*)alloc(B_*CI_*4);
  float*  pph  = (float*)alloc((size_t)400*128*4);
  __bf16* z = (__bf16*)phf32;      // z (bf16 12.85MB) reuses phf32 (dead after k_pool)

  k_wconv<<<128, 256, 0, stream>>>(wt, wp, wg, zw, wth, wtl, wph, wpl, wgh, wgl, zwh, zwl);
  k_proj3<<<NBLK_, 256, 0, stream>>>(x, wth, wtl, wph, wpl, wgh, wgl, th_hi, th_lo, phf32, ggf);
  k_pool<<<400, 256, 0, stream>>>(phf32, ggf, phph, phpl, ggp, pph);
  k_phmean2<<<2, 256, 0, stream>>>(pph, phmean);
  k_attn<<<NBLK2_, 256, 0, stream>>>(th_hi, th_lo, phph, phpl, ggp, phmean, y);
  k_zproj<<<NBLK_, 256, 0, stream>>>(y, zwh, zwl, z, pS, pQ);
  k_stats<<<256, 256, 0, stream>>>(pS, pQ, gamma, beta, coef);
  k_final<<<(B_*C_*N_/8 + 255)/256, 256, 0, stream>>>(x, z, coef, out);
}